// Round 12
// baseline (135.062 us; speedup 1.0000x reference)
//
#include <hip/hip_runtime.h>

// InfiniAttention — Round 22: R21 base (134.4us) + ONE change: kill the hs->hsb cast
// pass. k1 stages A directly from fp32 hs via reg-staging (4x float4 -> cvt -> 2x
// ds_write_b128 into the SAME linear LDS layout GL_LDS produced: slab s, thread tid ->
// As[s*2048 + tid*8]). Conversion = same RTN cast kprep used -> bitwise-identical A.
// kprep drops to 336 blocks (weights/memT/seed, ~5MB). hs fp32 (16MB) is L3-resident
// across k1's 6 y-passes. Everything else byte-identical to R21.

#define HIDDEN 1024
#define DMEM 256
#define BATCH 4
#define SEQ 1024
#define MTOT (BATCH * SEQ)      // 4096
#define CHUNK 128
#define NCH (SEQ / CHUNK)       // 8
#define NCHT (BATCH * NCH)      // 32
#define EPSF 1e-6f

typedef __bf16 bf16x8 __attribute__((ext_vector_type(8)));
typedef __bf16 bf16x4 __attribute__((ext_vector_type(4)));
typedef float f32x4 __attribute__((ext_vector_type(4)));

#define GL_LDS(g, l)                                                                   \
  __builtin_amdgcn_global_load_lds((const __attribute__((address_space(1))) void*)(g), \
                                   (__attribute__((address_space(3))) void*)(l), 16, 0, 0)

__device__ __forceinline__ float elu1(float x) { return x > 0.f ? x + 1.f : __expf(x); }

// Stage a 128-row x 64-col tile as two 32-col slabs (slab h at sm + h*4096).
__device__ __forceinline__ void stage128(const __bf16* p, long ld, int k0, __bf16* sm,
                                         int wave) {
  GL_LDS(p + k0, sm + wave * 512);
  GL_LDS(p + (size_t)64 * ld + k0, sm + 2048 + wave * 512);
  GL_LDS(p + k0 + 32, sm + 4096 + wave * 512);
  GL_LDS(p + (size_t)64 * ld + k0 + 32, sm + 4096 + 2048 + wave * 512);
}
// Stage a 64-row x 64-col tile as two slabs (slab h at sm + h*2048).
__device__ __forceinline__ void stage64(const __bf16* p, int k0, __bf16* sm, int wave) {
  GL_LDS(p + k0, sm + wave * 512);
  GL_LDS(p + k0 + 32, sm + 2048 + wave * 512);
}

// 64x128 tile, BK=64. Accumulates into acc.
__device__ __forceinline__ void gemm64_bk64(const __bf16* aptr, const __bf16* bptr, long ldb,
                                            int klen, __bf16* smA, __bf16* smB, int wave,
                                            int wr, int wc, int quad, int l16,
                                            f32x4 (&acc)[2][4]) {
  for (int k0 = 0; k0 < klen; k0 += 64) {
    stage64(aptr, k0, smA, wave);
    stage128(bptr, ldb, k0, smB, wave);
    __syncthreads();
#pragma unroll
    for (int h = 0; h < 2; ++h) {
      bf16x8 aF[2], bF[4];
#pragma unroll
      for (int i = 0; i < 2; ++i)
        aF[i] = *reinterpret_cast<const bf16x8*>(smA + h * 2048 +
                                                 (wr * 32 + i * 16 + l16) * 32 + quad * 8);
#pragma unroll
      for (int j = 0; j < 4; ++j)
        bF[j] = *reinterpret_cast<const bf16x8*>(smB + h * 4096 +
                                                 (wc * 64 + j * 16 + l16) * 32 + quad * 8);
#pragma unroll
      for (int i = 0; i < 2; ++i)
#pragma unroll
        for (int j = 0; j < 4; ++j)
          acc[i][j] = __builtin_amdgcn_mfma_f32_16x16x32_bf16(aF[i], bF[j], acc[i][j], 0, 0, 0);
    }
    __syncthreads();
  }
}

// -- kprep: weights casts + memT + FULL seed only (hs cast eliminated). grid 336 --
// b<192 wqkv | 192..255 wo | 256..271 memT | 272..335 seed
__global__ __launch_bounds__(256) void kprep(
    const float* __restrict__ wq, const float* __restrict__ wk, const float* __restrict__ wv,
    const float* __restrict__ wo, const float* __restrict__ mem, __bf16* __restrict__ wqkvb,
    __bf16* __restrict__ wob, __bf16* __restrict__ memT, float* __restrict__ out) {
  __shared__ float s[64][65];
  int b = blockIdx.x, tid = threadIdx.x;
  if (b < 192) {
    int mat = b >> 6;  // 0..2
    const float* src = (mat == 0) ? wq : (mat == 1) ? wk : wv;
    __bf16* dst = wqkvb + (size_t)mat * (DMEM * HIDDEN);
#pragma unroll
    for (int it = 0; it < 4; ++it) {
      int i = (b & 63) * 1024 + it * 256 + tid;
      float4 f = reinterpret_cast<const float4*>(src)[i];
      bf16x4 h = {(__bf16)f.x, (__bf16)f.y, (__bf16)f.z, (__bf16)f.w};
      reinterpret_cast<bf16x4*>(dst)[i] = h;
    }
  } else if (b < 256) {
    int t = b - 192;  // 0..63
#pragma unroll
    for (int it = 0; it < 4; ++it) {
      int i = t * 1024 + it * 256 + tid;
      float4 f = reinterpret_cast<const float4*>(wo)[i];
      bf16x4 h = {(__bf16)f.x, (__bf16)f.y, (__bf16)f.z, (__bf16)f.w};
      reinterpret_cast<bf16x4*>(wob)[i] = h;
    }
  } else if (b < 272) {
    int t = b - 256;
    int bx = t & 3, by = t >> 2;
    int r0 = tid >> 6, col = tid & 63;
#pragma unroll
    for (int it = 0; it < 16; ++it) {
      int row = it * 4 + r0;
      s[row][col] = mem[(size_t)(by * 64 + row) * DMEM + bx * 64 + col];
    }
    __syncthreads();
#pragma unroll
    for (int it = 0; it < 16; ++it) {
      int row = it * 4 + r0;
      memT[(size_t)(bx * 64 + row) * DMEM + by * 64 + col] = (__bf16)s[col][row];
    }
  } else {  // FULL seed: 64 blocks x 256 thr x float4 = 65536 floats
    int g = (b - 272) * 256 + tid;
    reinterpret_cast<float4*>(out + (size_t)MTOT * HIDDEN)[g] =
        reinterpret_cast<const float4*>(mem)[g];
  }
}

// -- K1: fused QKV projection, 64x128 BK=64, grid (64,6). A staged from fp32 hs
//    (reg-stage: 4x float4 -> cvt -> 2x ds_write_b128, identical LDS layout). --
__global__ __launch_bounds__(256) void k1_qkv_mfma(
    const float* __restrict__ hs, const __bf16* __restrict__ W, __bf16* __restrict__ sqb,
    __bf16* __restrict__ skb, __bf16* __restrict__ skT, __bf16* __restrict__ vT) {
  __shared__ __bf16 As[4096];
  __shared__ __bf16 Bs[8192];
  int tid = threadIdx.x;
  int lane = tid & 63, wave = tid >> 6;
  int m0 = blockIdx.x * 64;
  int by = blockIdx.y;
  int wsel = by >> 1, n0 = (by & 1) * 128;
  const float* ap = hs + (size_t)(m0 + (tid >> 2)) * HIDDEN + ((tid & 3) << 3);
  const __bf16* bptr = W + (size_t)(by * 128 + (tid >> 2)) * HIDDEN + ((tid & 3) << 3);
  int wr = wave >> 1, wc = wave & 1, quad = lane >> 4, l16 = lane & 15;
  f32x4 acc[2][4] = {};
  for (int k0 = 0; k0 < HIDDEN; k0 += 64) {
    // A: fp32 -> bf16 reg-stage into the GL_LDS-equivalent linear layout
    float4 f0 = *reinterpret_cast<const float4*>(ap + k0);
    float4 f1 = *reinterpret_cast<const float4*>(ap + k0 + 4);
    float4 f2 = *reinterpret_cast<const float4*>(ap + k0 + 32);
    float4 f3 = *reinterpret_cast<const float4*>(ap + k0 + 36);
    stage128(bptr, HIDDEN, k0, Bs, wave);
    bf16x8 a0 = {(__bf16)f0.x, (__bf16)f0.y, (__bf16)f0.z, (__bf16)f0.w,
                 (__bf16)f1.x, (__bf16)f1.y, (__bf16)f1.z, (__bf16)f1.w};
    bf16x8 a1 = {(__bf16)f2.x, (__bf16)f2.y, (__bf16)f2.z, (__bf16)f2.w,
                 (__bf16)f3.x, (__bf16)f3.y, (__bf16)f3.z, (__bf16)f3.w};
    *reinterpret_cast<bf16x8*>(As + tid * 8) = a0;
    *reinterpret_cast<bf16x8*>(As + 2048 + tid * 8) = a1;
    __syncthreads();
#pragma unroll
    for (int h = 0; h < 2; ++h) {
      bf16x8 aF[2], bF[4];
#pragma unroll
      for (int i = 0; i < 2; ++i)
        aF[i] = *reinterpret_cast<const bf16x8*>(As + h * 2048 +
                                                 (wr * 32 + i * 16 + l16) * 32 + quad * 8);
#pragma unroll
      for (int j = 0; j < 4; ++j)
        bF[j] = *reinterpret_cast<const bf16x8*>(Bs + h * 4096 +
                                                 (wc * 64 + j * 16 + l16) * 32 + quad * 8);
#pragma unroll
      for (int i = 0; i < 2; ++i)
#pragma unroll
        for (int j = 0; j < 4; ++j)
          acc[i][j] = __builtin_amdgcn_mfma_f32_16x16x32_bf16(aF[i], bF[j], acc[i][j], 0, 0, 0);
    }
    __syncthreads();
  }
#pragma unroll
  for (int i = 0; i < 2; ++i)
#pragma unroll
    for (int j = 0; j < 4; ++j) {
      int mb = m0 + wr * 32 + i * 16 + quad * 4;
      int n = n0 + wc * 64 + j * 16 + l16;
      if (wsel == 0) {
#pragma unroll
        for (int r = 0; r < 4; ++r) sqb[(size_t)(mb + r) * DMEM + n] = (__bf16)elu1(acc[i][j][r]);
      } else if (wsel == 1) {
        bf16x4 t;
#pragma unroll
        for (int r = 0; r < 4; ++r) {
          float v = elu1(acc[i][j][r]);
          skb[(size_t)(mb + r) * DMEM + n] = (__bf16)v;
          t[r] = (__bf16)v;
        }
        *reinterpret_cast<bf16x4*>(skT + (size_t)n * MTOT + mb) = t;
      } else {
        bf16x4 t;
#pragma unroll
        for (int r = 0; r < 4; ++r) t[r] = (__bf16)acc[i][j][r];
        *reinterpret_cast<bf16x4*>(vT + (size_t)n * MTOT + mb) = t;
      }
    }
}

// ------- kC: chunk-KV 64x128 (y<8) + causal scores (y=8,9) + ksum (y=10). grid (32,11) ------
__global__ __launch_bounds__(256) void kC(const __bf16* __restrict__ vT,
                                          const __bf16* __restrict__ skT,
                                          const __bf16* __restrict__ sqb,
                                          const __bf16* __restrict__ skb,
                                          __bf16* __restrict__ kvcT, __bf16* __restrict__ scb,
                                          float* __restrict__ ksc) {
  __shared__ __bf16 As[4096];
  __shared__ __bf16 Bs[8192];
  int tid = threadIdx.x;
  int c = blockIdx.x;
  int y = blockIdx.y;
  if (y == 10) {
    int d = tid;
    float s = 0.f;
    for (int i = 0; i < CHUNK; ++i) s += (float)skb[(size_t)(c * CHUNK + i) * DMEM + d];
    ksc[c * DMEM + d] = s;
    return;
  }
  int lane = tid & 63, wave = tid >> 6;
  int wr = wave >> 1, wc = wave & 1, quad = lane >> 4, l16 = lane & 15;
  if (y < 8) {  // kvcT[c][e][d] = sum_s vT[e,s]*skT[d,s], 64x128 tile
    int e0 = (y >> 1) * 64, d0 = (y & 1) * 128;
    const __bf16* aptr = vT + (size_t)(e0 + (tid >> 2)) * MTOT + c * CHUNK + ((tid & 3) << 3);
    const __bf16* bptr = skT + (size_t)(d0 + (tid >> 2)) * MTOT + c * CHUNK + ((tid & 3) << 3);
    f32x4 acc[2][4] = {};
    gemm64_bk64(aptr, bptr, MTOT, CHUNK, As, Bs, wave, wr, wc, quad, l16, acc);
#pragma unroll
    for (int i = 0; i < 2; ++i)
#pragma unroll
      for (int j = 0; j < 4; ++j)
#pragma unroll
        for (int r = 0; r < 4; ++r) {
          int e = e0 + wr * 32 + i * 16 + quad * 4 + r;
          int d = d0 + wc * 64 + j * 16 + l16;
          kvcT[(size_t)c * DMEM * DMEM + (size_t)e * DMEM + d] = (__bf16)acc[i][j][r];
        }
  } else {  // causal scores, i0 = (y-8)*64
    int i0 = (y - 8) * 64;
    const __bf16* aptr = sqb + (size_t)(c * CHUNK + i0 + (tid >> 2)) * DMEM + ((tid & 3) << 3);
    const __bf16* bptr = skb + (size_t)(c * CHUNK + (tid >> 2)) * DMEM + ((tid & 3) << 3);
    f32x4 acc[2][4] = {};
    gemm64_bk64(aptr, bptr, DMEM, DMEM, As, Bs, wave, wr, wc, quad, l16, acc);
#pragma unroll
    for (int i = 0; i < 2; ++i)
#pragma unroll
      for (int j = 0; j < 4; ++j)
#pragma unroll
        for (int r = 0; r < 4; ++r) {
          int ii = i0 + wr * 32 + i * 16 + quad * 4 + r;
          int jj = wc * 64 + j * 16 + l16;
          scb[(size_t)c * CHUNK * CHUNK + (size_t)ii * CHUNK + jj] =
              (jj <= ii) ? (__bf16)acc[i][j][r] : (__bf16)0.f;
        }
  }
}

// ---------------- kD: vectorized prefix (vt<128) + row scalars (vt>=128). grid 1152 -------
__global__ __launch_bounds__(256) void kD(const __bf16* __restrict__ kvcT,
                                          __bf16* __restrict__ kvpT,
                                          const float* __restrict__ ksc,
                                          const __bf16* __restrict__ scb,
                                          const __bf16* __restrict__ sqb,
                                          const __bf16* __restrict__ skb,
                                          const float* __restrict__ mnorm,
                                          float* __restrict__ den, float* __restrict__ qn,
                                          float* __restrict__ kn) {
  int vt = blockIdx.x;
  int tid = threadIdx.x;
  if (vt < 128) {
    int batch = vt >> 5;
    size_t idx8 = (size_t)(((vt & 31) * 256 + tid)) * 8;
    bf16x8 t[NCH];
#pragma unroll
    for (int c = 0; c < NCH; ++c)
      t[c] = *reinterpret_cast<const bf16x8*>(kvcT +
                                              (size_t)(batch * NCH + c) * DMEM * DMEM + idx8);
    float run[8] = {};
#pragma unroll
    for (int c = 0; c < NCH; ++c) {
      bf16x8 o;
#pragma unroll
      for (int r = 0; r < 8; ++r) o[r] = (__bf16)run[r];
      *reinterpret_cast<bf16x8*>(kvpT + (size_t)(batch * NCH + c) * DMEM * DMEM + idx8) = o;
#pragma unroll
      for (int r = 0; r < 8; ++r) run[r] += (float)t[c][r];
    }
  } else {
    int wave = tid >> 6, lane = tid & 63;
    int m = (vt - 128) * 4 + wave;
    int c = m >> 7;
    int i = m & 127;
    int cb = c & ~7;
    int cnt = c - cb;  // 0..7
    float s_sc = 0.f, s_d2 = 0.f, s_qn = 0.f, s_kn = 0.f;
    for (int j = lane; j < CHUNK; j += 64)
      s_sc += (float)scb[(size_t)c * CHUNK * CHUNK + (size_t)i * CHUNK + j];
    for (int d = lane; d < DMEM; d += 64) {
      float q = (float)sqb[(size_t)m * DMEM + d];
      float k = (float)skb[(size_t)m * DMEM + d];
      float kp = 0.f;
#pragma unroll
      for (int cc = 0; cc < 7; ++cc) {
        float v = ksc[(cb + cc) * DMEM + d];
        kp += (cc < cnt) ? v : 0.f;
      }
      s_d2 += q * kp;
      s_qn += q * mnorm[d];
      s_kn += k * mnorm[d];
    }
#pragma unroll
    for (int off = 32; off > 0; off >>= 1) {
      s_sc += __shfl_down(s_sc, off);
      s_d2 += __shfl_down(s_d2, off);
      s_qn += __shfl_down(s_qn, off);
      s_kn += __shfl_down(s_kn, off);
    }
    if (lane == 0) {
      den[m] = s_sc + s_d2;
      qn[m] = s_qn;
      kn[m] = s_kn;
    }
  }
}

// ---------------- kE: combine (bid<128) + delta-v (128..255). grid 256 ----------------
__global__ __launch_bounds__(256) void kE(const __bf16* __restrict__ scb,
                                          const __bf16* __restrict__ sqb,
                                          const __bf16* __restrict__ skb,
                                          const __bf16* __restrict__ vT,
                                          const __bf16* __restrict__ kvpT,
                                          const __bf16* __restrict__ memT,
                                          const float* __restrict__ den,
                                          const float* __restrict__ qn,
                                          const float* __restrict__ kn,
                                          const float* __restrict__ gate,
                                          const float* __restrict__ mnorm,
                                          __bf16* __restrict__ combb, __bf16* __restrict__ dvT) {
  __shared__ __bf16 As[4096];
  __shared__ __bf16 B1s[8192];
  __shared__ __bf16 B2s[8192];
  __shared__ float warr[4];
  int tid = threadIdx.x;
  int lane = tid & 63, wave = tid >> 6;
  int wr = wave >> 1, wc = wave & 1, quad = lane >> 4, l16 = lane & 15;
  int bid = blockIdx.x;
  if (bid < 128) {  // combine
    float mv = mnorm[tid];
#pragma unroll
    for (int off = 32; off > 0; off >>= 1) mv += __shfl_down(mv, off);
    if (lane == 0) warr[wave] = mv;
    __syncthreads();
    float fl = ((warr[0] + warr[1] + warr[2] + warr[3]) < EPSF) ? 0.f : 1.f;
    __syncthreads();
    int c = bid >> 2, yy = bid & 3;
    int i0 = (yy >> 1) * 64, e0 = (yy & 1) * 128;
    f32x4 acc_loc[2][4] = {};
    f32x4 acc_mem[2][4] = {};
    {  // phase 1: scores @ v (K=128)
      const __bf16* aptr =
          scb + (size_t)c * CHUNK * CHUNK + (size_t)(i0 + (tid >> 2)) * CHUNK + ((tid & 3) << 3);
      const __bf16* bptr = vT + (size_t)(e0 + (tid >> 2)) * MTOT + c * CHUNK + ((tid & 3) << 3);
      gemm64_bk64(aptr, bptr, MTOT, CHUNK, As, B1s, wave, wr, wc, quad, l16, acc_loc);
    }
    {  // phase 2: sq @ kvp + sq @ memT (K=256, dual B)
      const __bf16* aptr = sqb + (size_t)(c * CHUNK + i0 + (tid >> 2)) * DMEM + ((tid & 3) << 3);
      const __bf16* b1ptr =
          kvpT + (size_t)c * DMEM * DMEM + (size_t)(e0 + (tid >> 2)) * DMEM + ((tid & 3) << 3);
      const __bf16* b2ptr = memT + (size_t)(e0 + (tid >> 2)) * DMEM + ((tid & 3) << 3);
      for (int k0 = 0; k0 < DMEM; k0 += 64) {
        stage64(aptr, k0, As, wave);
        stage128(b1ptr, DMEM, k0, B1s, wave);
        stage128(b2ptr, DMEM, k0, B2s, wave);
        __syncthreads();
#pragma unroll
        for (int h = 0; h < 2; ++h) {
          bf16x8 aF[2], b1F[4], b2F[4];
#pragma unroll
          for (int i = 0; i < 2; ++i)
            aF[i] = *reinterpret_cast<const bf16x8*>(As + h * 2048 +
                                                     (wr * 32 + i * 16 + l16) * 32 + quad * 8);
#pragma unroll
          for (int j = 0; j < 4; ++j) {
            b1F[j] = *reinterpret_cast<const bf16x8*>(B1s + h * 4096 +
                                                      (wc * 64 + j * 16 + l16) * 32 + quad * 8);
            b2F[j] = *reinterpret_cast<const bf16x8*>(B2s + h * 4096 +
                                                      (wc * 64 + j * 16 + l16) * 32 + quad * 8);
          }
#pragma unroll
          for (int i = 0; i < 2; ++i)
#pragma unroll
            for (int j = 0; j < 4; ++j) {
              acc_loc[i][j] =
                  __builtin_amdgcn_mfma_f32_16x16x32_bf16(aF[i], b1F[j], acc_loc[i][j], 0, 0, 0);
              acc_mem[i][j] =
                  __builtin_amdgcn_mfma_f32_16x16x32_bf16(aF[i], b2F[j], acc_mem[i][j], 0, 0, 0);
            }
        }
        __syncthreads();
      }
    }
    float g = 1.f / (1.f + __expf(-gate[0]));
#pragma unroll
    for (int i = 0; i < 2; ++i) {
      int mb = c * CHUNK + i0 + wr * 32 + i * 16 + quad * 4;
      float dn[4], qv[4];
#pragma unroll
      for (int r = 0; r < 4; ++r) {
        dn[r] = fmaxf(den[mb + r], EPSF);
        qv[r] = fmaxf(qn[mb + r], EPSF);
      }
#pragma unroll
      for (int j = 0; j < 4; ++j) {
        int e = e0 + wc * 64 + j * 16 + l16;
#pragma unroll
        for (int r = 0; r < 4; ++r) {
          float comb = g * fl * acc_mem[i][j][r] / qv[r] + (1.f - g) * acc_loc[i][j][r] / dn[r];
          combb[(size_t)(mb + r) * DMEM + e] = (__bf16)comb;
        }
      }
    }
  } else {  // dv = v - (sk@memT)/kn -> dvT, 64x128 tiles
    int t = bid - 128;
    int m0 = (t >> 1) * 64, n0 = (t & 1) * 128;
    const __bf16* aptr = skb + (size_t)(m0 + (tid >> 2)) * DMEM + ((tid & 3) << 3);
    const __bf16* bptr = memT + (size_t)(n0 + (tid >> 2)) * DMEM + ((tid & 3) << 3);
    f32x4 acc[2][4] = {};
    gemm64_bk64(aptr, bptr, DMEM, DMEM, As, B1s, wave, wr, wc, quad, l16, acc);
#pragma unroll
    for (int i = 0; i < 2; ++i) {
      int mb = m0 + wr * 32 + i * 16 + quad * 4;
      float kv[4];
#pragma unroll
      for (int r = 0; r < 4; ++r) kv[r] = fmaxf(kn[mb + r], EPSF);
#pragma unroll
      for (int j = 0; j < 4; ++j) {
        int n = n0 + wc * 64 + j * 16 + l16;
        bf16x4 vv = *reinterpret_cast<const bf16x4*>(vT + (size_t)n * MTOT + mb);
        bf16x4 tt;
#pragma unroll
        for (int r = 0; r < 4; ++r) tt[r] = (__bf16)((float)vv[r] - acc[i][j][r] / kv[r]);
        *reinterpret_cast<bf16x4*>(dvT + (size_t)n * MTOT + mb) = tt;
      }
    }
  }
}

// -- kF: out-proj 64x128 (bid<512) + mem-update split-K atomics (512..639) + norm (640).
//    grid 641 --
__global__ __launch_bounds__(256) void kF(const __bf16* __restrict__ combb,
                                          const __bf16* __restrict__ wob,
                                          const __bf16* __restrict__ skT,
                                          const __bf16* __restrict__ dvT,
                                          const float* __restrict__ ksc,
                                          const float* __restrict__ mnorm,
                                          float* __restrict__ out) {
  __shared__ __bf16 As[4096];
  __shared__ __bf16 Bs[8192];
  int tid = threadIdx.x;
  int bid = blockIdx.x;
  if (bid == 640) {  // new_memory_norm
    int d = tid;
    float s = 0.f;
    for (int c = 0; c < NCHT; ++c) s += ksc[c * DMEM + d];
    out[(size_t)MTOT * HIDDEN + DMEM * DMEM + d] = mnorm[d] + s * (1.f / (float)BATCH);
    return;
  }
  int lane = tid & 63, wave = tid >> 6;
  int wr = wave >> 1, wc = wave & 1, quad = lane >> 4, l16 = lane & 15;
  if (bid < 512) {  // output projection, 64x128 BK=64
    int m0 = (bid & 63) * 64, by = bid >> 6;  // by 0..7
    const __bf16* aptr = combb + (size_t)(m0 + (tid >> 2)) * DMEM + ((tid & 3) << 3);
    const __bf16* bptr = wob + (size_t)(by * 128 + (tid >> 2)) * DMEM + ((tid & 3) << 3);
    f32x4 acc[2][4] = {};
    gemm64_bk64(aptr, bptr, DMEM, DMEM, As, Bs, wave, wr, wc, quad, l16, acc);
#pragma unroll
    for (int i = 0; i < 2; ++i)
#pragma unroll
      for (int j = 0; j < 4; ++j)
#pragma unroll
        for (int r = 0; r < 4; ++r) {
          int m = m0 + wr * 32 + i * 16 + quad * 4 + r;
          int n = by * 128 + wc * 64 + j * 16 + l16;
          out[(size_t)m * HIDDEN + n] = acc[i][j][r];
        }
  } else {  // mem-update: 16-way split-K (K=256 each), 64x128 tiles, atomics
    int t = bid - 512;
    int kbase = (t >> 3) * 256;
    int yy = t & 7;
    int d0 = (yy >> 1) * 64, e0 = (yy & 1) * 128;
    const __bf16* aptr = skT + (size_t)(d0 + (tid >> 2)) * MTOT + kbase + ((tid & 3) << 3);
    const __bf16* bptr = dvT + (size_t)(e0 + (tid >> 2)) * MTOT + kbase + ((tid & 3) << 3);
    f32x4 acc[2][4] = {};
    gemm64_bk64(aptr, bptr, MTOT, 256, As, Bs, wave, wr, wc, quad, l16, acc);
    float* base = out + (size_t)MTOT * HIDDEN;
#pragma unroll
    for (int i = 0; i < 2; ++i)
#pragma unroll
      for (int j = 0; j < 4; ++j)
#pragma unroll
        for (int r = 0; r < 4; ++r) {
          int d = d0 + wr * 32 + i * 16 + quad * 4 + r;
          int e = e0 + wc * 64 + j * 16 + l16;
          atomicAdd(&base[(size_t)d * DMEM + e], acc[i][j][r] * (1.f / (float)MTOT));
        }
  }
}

extern "C" void kernel_launch(void* const* d_in, const int* in_sizes, int n_in,
                              void* d_out, int out_size, void* d_ws, size_t ws_size,
                              hipStream_t stream) {
  const float* hs = (const float*)d_in[0];
  const float* wq = (const float*)d_in[1];
  const float* wk = (const float*)d_in[2];
  const float* wv = (const float*)d_in[3];
  const float* wo = (const float*)d_in[4];
  const float* gate = (const float*)d_in[5];
  const float* mem = (const float*)d_in[6];
  const float* mnorm = (const float*)d_in[7];
  float* out = (float*)d_out;
  float* ws = (float*)d_ws;

  // fp32 region
  float* ksc = ws;          // 8192
  float* den = ksc + 8192;  // 4096
  float* qn = den + 4096;   // 4096
  float* kn = qn + 4096;    // 4096 (end 20480 floats)
  // bf16 region (hsb slot retained in layout but unused)
  __bf16* kvcT = (__bf16*)(ws + 20480);               // 2097152
  __bf16* hsb = kvcT + (size_t)NCHT * DMEM * DMEM;    // 4194304 (unused)
  __bf16* wqkvb = hsb + (size_t)MTOT * HIDDEN;        // 786432
  __bf16* wob = wqkvb + (size_t)3 * DMEM * HIDDEN;    // 262144
  __bf16* memT = wob + (size_t)HIDDEN * DMEM;         // 65536
  __bf16* sqb = memT + (size_t)DMEM * DMEM;           // 1048576
  __bf16* skb = sqb + (size_t)MTOT * DMEM;            // 1048576
  __bf16* skT = skb + (size_t)MTOT * DMEM;            // 1048576
  __bf16* vT = skT + (size_t)MTOT * DMEM;             // 1048576
  __bf16* scb = vT + (size_t)MTOT * DMEM;             // 524288
  __bf16* kvpT = scb + (size_t)NCHT * CHUNK * CHUNK;  // 2097152
  __bf16* combb = kvpT + (size_t)NCHT * DMEM * DMEM;  // 1048576
  __bf16* dvT = combb + (size_t)MTOT * DMEM;          // 1048576

  kprep<<<dim3(336), 256, 0, stream>>>(wq, wk, wv, wo, mem, wqkvb, wob, memT, out);
  k1_qkv_mfma<<<dim3(64, 6), 256, 0, stream>>>(hs, wqkvb, sqb, skb, skT, vT);
  kC<<<dim3(NCHT, 11), 256, 0, stream>>>(vT, skT, sqb, skb, kvcT, scb, ksc);
  kD<<<dim3(1152), 256, 0, stream>>>(kvcT, kvpT, ksc, scb, sqb, skb, mnorm, den, qn, kn);
  kE<<<dim3(256), 256, 0, stream>>>(scb, sqb, skb, vT, kvpT, memT, den, qn, kn, gate, mnorm,
                                    combb, dvT);
  kF<<<dim3(641), 256, 0, stream>>>(combb, wob, skT, dvT, ksc, mnorm, out);
}

// Round 13
// 133.894 us; speedup vs baseline: 1.0087x; 1.0087x over previous
//
#include <hip/hip_runtime.h>

// InfiniAttention — FINAL (R21 locked in; session best 134.4us, from 143.1 at start).
// Structure: 6-kernel pipeline. kprep (compact casts + memT + full new_memory seed),
// k1 QKV 64x128 MFMA (grid 384), kC chunk-KV/scores/ksum (32x11), kD prefix + row
// scalars w/ predicated-unroll den loop (1152), kE combine dual-B + dv (256),
// kF out-proj 64x128 + mem-update split-K atomics + norm (641).
// Session lessons: grid barriers cost ~60us/each on 8 non-coherent XCD L2s (fusion
// dead); latency-bound row-scalar kernels need max TLP (never trade waves for
// per-thread work); k1 tile ladder bracketed 64x128 optimal; kernel boundaries ~4us
// are the cheapest sync primitive on this chip.

#define HIDDEN 1024
#define DMEM 256
#define BATCH 4
#define SEQ 1024
#define MTOT (BATCH * SEQ)      // 4096
#define CHUNK 128
#define NCH (SEQ / CHUNK)       // 8
#define NCHT (BATCH * NCH)      // 32
#define EPSF 1e-6f

typedef __bf16 bf16x8 __attribute__((ext_vector_type(8)));
typedef __bf16 bf16x4 __attribute__((ext_vector_type(4)));
typedef float f32x4 __attribute__((ext_vector_type(4)));

#define GL_LDS(g, l)                                                                   \
  __builtin_amdgcn_global_load_lds((const __attribute__((address_space(1))) void*)(g), \
                                   (__attribute__((address_space(3))) void*)(l), 16, 0, 0)

__device__ __forceinline__ float elu1(float x) { return x > 0.f ? x + 1.f : __expf(x); }

// Stage a 128-row x 64-col tile as two 32-col slabs (slab h at sm + h*4096).
__device__ __forceinline__ void stage128(const __bf16* p, long ld, int k0, __bf16* sm,
                                         int wave) {
  GL_LDS(p + k0, sm + wave * 512);
  GL_LDS(p + (size_t)64 * ld + k0, sm + 2048 + wave * 512);
  GL_LDS(p + k0 + 32, sm + 4096 + wave * 512);
  GL_LDS(p + (size_t)64 * ld + k0 + 32, sm + 4096 + 2048 + wave * 512);
}
// Stage a 64-row x 64-col tile as two slabs (slab h at sm + h*2048).
__device__ __forceinline__ void stage64(const __bf16* p, int k0, __bf16* sm, int wave) {
  GL_LDS(p + k0, sm + wave * 512);
  GL_LDS(p + k0 + 32, sm + 2048 + wave * 512);
}

// 64x128 tile, BK=64. Accumulates into acc.
__device__ __forceinline__ void gemm64_bk64(const __bf16* aptr, const __bf16* bptr, long ldb,
                                            int klen, __bf16* smA, __bf16* smB, int wave,
                                            int wr, int wc, int quad, int l16,
                                            f32x4 (&acc)[2][4]) {
  for (int k0 = 0; k0 < klen; k0 += 64) {
    stage64(aptr, k0, smA, wave);
    stage128(bptr, ldb, k0, smB, wave);
    __syncthreads();
#pragma unroll
    for (int h = 0; h < 2; ++h) {
      bf16x8 aF[2], bF[4];
#pragma unroll
      for (int i = 0; i < 2; ++i)
        aF[i] = *reinterpret_cast<const bf16x8*>(smA + h * 2048 +
                                                 (wr * 32 + i * 16 + l16) * 32 + quad * 8);
#pragma unroll
      for (int j = 0; j < 4; ++j)
        bF[j] = *reinterpret_cast<const bf16x8*>(smB + h * 4096 +
                                                 (wc * 64 + j * 16 + l16) * 32 + quad * 8);
#pragma unroll
      for (int i = 0; i < 2; ++i)
#pragma unroll
        for (int j = 0; j < 4; ++j)
          acc[i][j] = __builtin_amdgcn_mfma_f32_16x16x32_bf16(aF[i], bF[j], acc[i][j], 0, 0, 0);
    }
    __syncthreads();
  }
}

// -- kprep: compact casts + memT + FULL seed. grid 1360 --
// b<1024 hs(4xf4) | 1024..1215 wqkv | 1216..1279 wo | 1280..1295 memT | 1296..1359 seed
__global__ __launch_bounds__(256) void kprep(
    const float* __restrict__ hs, const float* __restrict__ wq, const float* __restrict__ wk,
    const float* __restrict__ wv, const float* __restrict__ wo, const float* __restrict__ mem,
    __bf16* __restrict__ hsb, __bf16* __restrict__ wqkvb, __bf16* __restrict__ wob,
    __bf16* __restrict__ memT, float* __restrict__ out) {
  __shared__ float s[64][65];
  int b = blockIdx.x, tid = threadIdx.x;
  if (b < 1024) {
#pragma unroll
    for (int it = 0; it < 4; ++it) {
      int i = b * 1024 + it * 256 + tid;
      float4 f = reinterpret_cast<const float4*>(hs)[i];
      bf16x4 h = {(__bf16)f.x, (__bf16)f.y, (__bf16)f.z, (__bf16)f.w};
      reinterpret_cast<bf16x4*>(hsb)[i] = h;
    }
  } else if (b < 1216) {
    int t = b - 1024;  // 0..191
    int mat = t >> 6;  // 0..2
    const float* src = (mat == 0) ? wq : (mat == 1) ? wk : wv;
    __bf16* dst = wqkvb + (size_t)mat * (DMEM * HIDDEN);
#pragma unroll
    for (int it = 0; it < 4; ++it) {
      int i = (t & 63) * 1024 + it * 256 + tid;
      float4 f = reinterpret_cast<const float4*>(src)[i];
      bf16x4 h = {(__bf16)f.x, (__bf16)f.y, (__bf16)f.z, (__bf16)f.w};
      reinterpret_cast<bf16x4*>(dst)[i] = h;
    }
  } else if (b < 1280) {
    int t = b - 1216;  // 0..63
#pragma unroll
    for (int it = 0; it < 4; ++it) {
      int i = t * 1024 + it * 256 + tid;
      float4 f = reinterpret_cast<const float4*>(wo)[i];
      bf16x4 h = {(__bf16)f.x, (__bf16)f.y, (__bf16)f.z, (__bf16)f.w};
      reinterpret_cast<bf16x4*>(wob)[i] = h;
    }
  } else if (b < 1296) {
    int t = b - 1280;
    int bx = t & 3, by = t >> 2;
    int r0 = tid >> 6, col = tid & 63;
#pragma unroll
    for (int it = 0; it < 16; ++it) {
      int row = it * 4 + r0;
      s[row][col] = mem[(size_t)(by * 64 + row) * DMEM + bx * 64 + col];
    }
    __syncthreads();
#pragma unroll
    for (int it = 0; it < 16; ++it) {
      int row = it * 4 + r0;
      memT[(size_t)(bx * 64 + row) * DMEM + by * 64 + col] = (__bf16)s[col][row];
    }
  } else {  // FULL seed: 64 blocks x 256 thr x float4 = 65536 floats
    int g = (b - 1296) * 256 + tid;
    reinterpret_cast<float4*>(out + (size_t)MTOT * HIDDEN)[g] =
        reinterpret_cast<const float4*>(mem)[g];
  }
}

// ---------------- K1: fused QKV projection, 64x128 BK=64, grid (64,6) ----------------
__global__ __launch_bounds__(256) void k1_qkv_mfma(
    const __bf16* __restrict__ X, const __bf16* __restrict__ W, __bf16* __restrict__ sqb,
    __bf16* __restrict__ skb, __bf16* __restrict__ skT, __bf16* __restrict__ vT) {
  __shared__ __bf16 As[4096];
  __shared__ __bf16 Bs[8192];
  int tid = threadIdx.x;
  int lane = tid & 63, wave = tid >> 6;
  int m0 = blockIdx.x * 64;
  int by = blockIdx.y;
  int wsel = by >> 1, n0 = (by & 1) * 128;
  const __bf16* aptr = X + (size_t)(m0 + (tid >> 2)) * HIDDEN + ((tid & 3) << 3);
  const __bf16* bptr = W + (size_t)(by * 128 + (tid >> 2)) * HIDDEN + ((tid & 3) << 3);
  int wr = wave >> 1, wc = wave & 1, quad = lane >> 4, l16 = lane & 15;
  f32x4 acc[2][4] = {};
  gemm64_bk64(aptr, bptr, HIDDEN, HIDDEN, As, Bs, wave, wr, wc, quad, l16, acc);
#pragma unroll
  for (int i = 0; i < 2; ++i)
#pragma unroll
    for (int j = 0; j < 4; ++j) {
      int mb = m0 + wr * 32 + i * 16 + quad * 4;
      int n = n0 + wc * 64 + j * 16 + l16;
      if (wsel == 0) {
#pragma unroll
        for (int r = 0; r < 4; ++r) sqb[(size_t)(mb + r) * DMEM + n] = (__bf16)elu1(acc[i][j][r]);
      } else if (wsel == 1) {
        bf16x4 t;
#pragma unroll
        for (int r = 0; r < 4; ++r) {
          float v = elu1(acc[i][j][r]);
          skb[(size_t)(mb + r) * DMEM + n] = (__bf16)v;
          t[r] = (__bf16)v;
        }
        *reinterpret_cast<bf16x4*>(skT + (size_t)n * MTOT + mb) = t;
      } else {
        bf16x4 t;
#pragma unroll
        for (int r = 0; r < 4; ++r) t[r] = (__bf16)acc[i][j][r];
        *reinterpret_cast<bf16x4*>(vT + (size_t)n * MTOT + mb) = t;
      }
    }
}

// ------- kC: chunk-KV 64x128 (y<8) + causal scores (y=8,9) + ksum (y=10). grid (32,11) ------
__global__ __launch_bounds__(256) void kC(const __bf16* __restrict__ vT,
                                          const __bf16* __restrict__ skT,
                                          const __bf16* __restrict__ sqb,
                                          const __bf16* __restrict__ skb,
                                          __bf16* __restrict__ kvcT, __bf16* __restrict__ scb,
                                          float* __restrict__ ksc) {
  __shared__ __bf16 As[4096];
  __shared__ __bf16 Bs[8192];
  int tid = threadIdx.x;
  int c = blockIdx.x;
  int y = blockIdx.y;
  if (y == 10) {
    int d = tid;
    float s = 0.f;
    for (int i = 0; i < CHUNK; ++i) s += (float)skb[(size_t)(c * CHUNK + i) * DMEM + d];
    ksc[c * DMEM + d] = s;
    return;
  }
  int lane = tid & 63, wave = tid >> 6;
  int wr = wave >> 1, wc = wave & 1, quad = lane >> 4, l16 = lane & 15;
  if (y < 8) {  // kvcT[c][e][d] = sum_s vT[e,s]*skT[d,s], 64x128 tile
    int e0 = (y >> 1) * 64, d0 = (y & 1) * 128;
    const __bf16* aptr = vT + (size_t)(e0 + (tid >> 2)) * MTOT + c * CHUNK + ((tid & 3) << 3);
    const __bf16* bptr = skT + (size_t)(d0 + (tid >> 2)) * MTOT + c * CHUNK + ((tid & 3) << 3);
    f32x4 acc[2][4] = {};
    gemm64_bk64(aptr, bptr, MTOT, CHUNK, As, Bs, wave, wr, wc, quad, l16, acc);
#pragma unroll
    for (int i = 0; i < 2; ++i)
#pragma unroll
      for (int j = 0; j < 4; ++j)
#pragma unroll
        for (int r = 0; r < 4; ++r) {
          int e = e0 + wr * 32 + i * 16 + quad * 4 + r;
          int d = d0 + wc * 64 + j * 16 + l16;
          kvcT[(size_t)c * DMEM * DMEM + (size_t)e * DMEM + d] = (__bf16)acc[i][j][r];
        }
  } else {  // causal scores, i0 = (y-8)*64
    int i0 = (y - 8) * 64;
    const __bf16* aptr = sqb + (size_t)(c * CHUNK + i0 + (tid >> 2)) * DMEM + ((tid & 3) << 3);
    const __bf16* bptr = skb + (size_t)(c * CHUNK + (tid >> 2)) * DMEM + ((tid & 3) << 3);
    f32x4 acc[2][4] = {};
    gemm64_bk64(aptr, bptr, DMEM, DMEM, As, Bs, wave, wr, wc, quad, l16, acc);
#pragma unroll
    for (int i = 0; i < 2; ++i)
#pragma unroll
      for (int j = 0; j < 4; ++j)
#pragma unroll
        for (int r = 0; r < 4; ++r) {
          int ii = i0 + wr * 32 + i * 16 + quad * 4 + r;
          int jj = wc * 64 + j * 16 + l16;
          scb[(size_t)c * CHUNK * CHUNK + (size_t)ii * CHUNK + jj] =
              (jj <= ii) ? (__bf16)acc[i][j][r] : (__bf16)0.f;
        }
  }
}

// ---------------- kD: vectorized prefix (vt<128) + row scalars (vt>=128). grid 1152 -------
__global__ __launch_bounds__(256) void kD(const __bf16* __restrict__ kvcT,
                                          __bf16* __restrict__ kvpT,
                                          const float* __restrict__ ksc,
                                          const __bf16* __restrict__ scb,
                                          const __bf16* __restrict__ sqb,
                                          const __bf16* __restrict__ skb,
                                          const float* __restrict__ mnorm,
                                          float* __restrict__ den, float* __restrict__ qn,
                                          float* __restrict__ kn) {
  int vt = blockIdx.x;
  int tid = threadIdx.x;
  if (vt < 128) {
    int batch = vt >> 5;
    size_t idx8 = (size_t)(((vt & 31) * 256 + tid)) * 8;
    bf16x8 t[NCH];
#pragma unroll
    for (int c = 0; c < NCH; ++c)
      t[c] = *reinterpret_cast<const bf16x8*>(kvcT +
                                              (size_t)(batch * NCH + c) * DMEM * DMEM + idx8);
    float run[8] = {};
#pragma unroll
    for (int c = 0; c < NCH; ++c) {
      bf16x8 o;
#pragma unroll
      for (int r = 0; r < 8; ++r) o[r] = (__bf16)run[r];
      *reinterpret_cast<bf16x8*>(kvpT + (size_t)(batch * NCH + c) * DMEM * DMEM + idx8) = o;
#pragma unroll
      for (int r = 0; r < 8; ++r) run[r] += (float)t[c][r];
    }
  } else {
    int wave = tid >> 6, lane = tid & 63;
    int m = (vt - 128) * 4 + wave;
    int c = m >> 7;
    int i = m & 127;
    int cb = c & ~7;
    int cnt = c - cb;  // 0..7
    float s_sc = 0.f, s_d2 = 0.f, s_qn = 0.f, s_kn = 0.f;
    for (int j = lane; j < CHUNK; j += 64)
      s_sc += (float)scb[(size_t)c * CHUNK * CHUNK + (size_t)i * CHUNK + j];
    for (int d = lane; d < DMEM; d += 64) {
      float q = (float)sqb[(size_t)m * DMEM + d];
      float k = (float)skb[(size_t)m * DMEM + d];
      float kp = 0.f;
#pragma unroll
      for (int cc = 0; cc < 7; ++cc) {
        float v = ksc[(cb + cc) * DMEM + d];
        kp += (cc < cnt) ? v : 0.f;
      }
      s_d2 += q * kp;
      s_qn += q * mnorm[d];
      s_kn += k * mnorm[d];
    }
#pragma unroll
    for (int off = 32; off > 0; off >>= 1) {
      s_sc += __shfl_down(s_sc, off);
      s_d2 += __shfl_down(s_d2, off);
      s_qn += __shfl_down(s_qn, off);
      s_kn += __shfl_down(s_kn, off);
    }
    if (lane == 0) {
      den[m] = s_sc + s_d2;
      qn[m] = s_qn;
      kn[m] = s_kn;
    }
  }
}

// ---------------- kE: combine (bid<128) + delta-v (128..255). grid 256 ----------------
__global__ __launch_bounds__(256) void kE(const __bf16* __restrict__ scb,
                                          const __bf16* __restrict__ sqb,
                                          const __bf16* __restrict__ skb,
                                          const __bf16* __restrict__ vT,
                                          const __bf16* __restrict__ kvpT,
                                          const __bf16* __restrict__ memT,
                                          const float* __restrict__ den,
                                          const float* __restrict__ qn,
                                          const float* __restrict__ kn,
                                          const float* __restrict__ gate,
                                          const float* __restrict__ mnorm,
                                          __bf16* __restrict__ combb, __bf16* __restrict__ dvT) {
  __shared__ __bf16 As[4096];
  __shared__ __bf16 B1s[8192];
  __shared__ __bf16 B2s[8192];
  __shared__ float warr[4];
  int tid = threadIdx.x;
  int lane = tid & 63, wave = tid >> 6;
  int wr = wave >> 1, wc = wave & 1, quad = lane >> 4, l16 = lane & 15;
  int bid = blockIdx.x;
  if (bid < 128) {  // combine
    float mv = mnorm[tid];
#pragma unroll
    for (int off = 32; off > 0; off >>= 1) mv += __shfl_down(mv, off);
    if (lane == 0) warr[wave] = mv;
    __syncthreads();
    float fl = ((warr[0] + warr[1] + warr[2] + warr[3]) < EPSF) ? 0.f : 1.f;
    __syncthreads();
    int c = bid >> 2, yy = bid & 3;
    int i0 = (yy >> 1) * 64, e0 = (yy & 1) * 128;
    f32x4 acc_loc[2][4] = {};
    f32x4 acc_mem[2][4] = {};
    {  // phase 1: scores @ v (K=128)
      const __bf16* aptr =
          scb + (size_t)c * CHUNK * CHUNK + (size_t)(i0 + (tid >> 2)) * CHUNK + ((tid & 3) << 3);
      const __bf16* bptr = vT + (size_t)(e0 + (tid >> 2)) * MTOT + c * CHUNK + ((tid & 3) << 3);
      gemm64_bk64(aptr, bptr, MTOT, CHUNK, As, B1s, wave, wr, wc, quad, l16, acc_loc);
    }
    {  // phase 2: sq @ kvp + sq @ memT (K=256, dual B)
      const __bf16* aptr = sqb + (size_t)(c * CHUNK + i0 + (tid >> 2)) * DMEM + ((tid & 3) << 3);
      const __bf16* b1ptr =
          kvpT + (size_t)c * DMEM * DMEM + (size_t)(e0 + (tid >> 2)) * DMEM + ((tid & 3) << 3);
      const __bf16* b2ptr = memT + (size_t)(e0 + (tid >> 2)) * DMEM + ((tid & 3) << 3);
      for (int k0 = 0; k0 < DMEM; k0 += 64) {
        stage64(aptr, k0, As, wave);
        stage128(b1ptr, DMEM, k0, B1s, wave);
        stage128(b2ptr, DMEM, k0, B2s, wave);
        __syncthreads();
#pragma unroll
        for (int h = 0; h < 2; ++h) {
          bf16x8 aF[2], b1F[4], b2F[4];
#pragma unroll
          for (int i = 0; i < 2; ++i)
            aF[i] = *reinterpret_cast<const bf16x8*>(As + h * 2048 +
                                                     (wr * 32 + i * 16 + l16) * 32 + quad * 8);
#pragma unroll
          for (int j = 0; j < 4; ++j) {
            b1F[j] = *reinterpret_cast<const bf16x8*>(B1s + h * 4096 +
                                                      (wc * 64 + j * 16 + l16) * 32 + quad * 8);
            b2F[j] = *reinterpret_cast<const bf16x8*>(B2s + h * 4096 +
                                                      (wc * 64 + j * 16 + l16) * 32 + quad * 8);
          }
#pragma unroll
          for (int i = 0; i < 2; ++i)
#pragma unroll
            for (int j = 0; j < 4; ++j) {
              acc_loc[i][j] =
                  __builtin_amdgcn_mfma_f32_16x16x32_bf16(aF[i], b1F[j], acc_loc[i][j], 0, 0, 0);
              acc_mem[i][j] =
                  __builtin_amdgcn_mfma_f32_16x16x32_bf16(aF[i], b2F[j], acc_mem[i][j], 0, 0, 0);
            }
        }
        __syncthreads();
      }
    }
    float g = 1.f / (1.f + __expf(-gate[0]));
#pragma unroll
    for (int i = 0; i < 2; ++i) {
      int mb = c * CHUNK + i0 + wr * 32 + i * 16 + quad * 4;
      float dn[4], qv[4];
#pragma unroll
      for (int r = 0; r < 4; ++r) {
        dn[r] = fmaxf(den[mb + r], EPSF);
        qv[r] = fmaxf(qn[mb + r], EPSF);
      }
#pragma unroll
      for (int j = 0; j < 4; ++j) {
        int e = e0 + wc * 64 + j * 16 + l16;
#pragma unroll
        for (int r = 0; r < 4; ++r) {
          float comb = g * fl * acc_mem[i][j][r] / qv[r] + (1.f - g) * acc_loc[i][j][r] / dn[r];
          combb[(size_t)(mb + r) * DMEM + e] = (__bf16)comb;
        }
      }
    }
  } else {  // dv = v - (sk@memT)/kn -> dvT, 64x128 tiles
    int t = bid - 128;
    int m0 = (t >> 1) * 64, n0 = (t & 1) * 128;
    const __bf16* aptr = skb + (size_t)(m0 + (tid >> 2)) * DMEM + ((tid & 3) << 3);
    const __bf16* bptr = memT + (size_t)(n0 + (tid >> 2)) * DMEM + ((tid & 3) << 3);
    f32x4 acc[2][4] = {};
    gemm64_bk64(aptr, bptr, DMEM, DMEM, As, B1s, wave, wr, wc, quad, l16, acc);
#pragma unroll
    for (int i = 0; i < 2; ++i) {
      int mb = m0 + wr * 32 + i * 16 + quad * 4;
      float kv[4];
#pragma unroll
      for (int r = 0; r < 4; ++r) kv[r] = fmaxf(kn[mb + r], EPSF);
#pragma unroll
      for (int j = 0; j < 4; ++j) {
        int n = n0 + wc * 64 + j * 16 + l16;
        bf16x4 vv = *reinterpret_cast<const bf16x4*>(vT + (size_t)n * MTOT + mb);
        bf16x4 tt;
#pragma unroll
        for (int r = 0; r < 4; ++r) tt[r] = (__bf16)((float)vv[r] - acc[i][j][r] / kv[r]);
        *reinterpret_cast<bf16x4*>(dvT + (size_t)n * MTOT + mb) = tt;
      }
    }
  }
}

// -- kF: out-proj 64x128 (bid<512) + mem-update split-K atomics (512..639) + norm (640).
//    grid 641 --
__global__ __launch_bounds__(256) void kF(const __bf16* __restrict__ combb,
                                          const __bf16* __restrict__ wob,
                                          const __bf16* __restrict__ skT,
                                          const __bf16* __restrict__ dvT,
                                          const float* __restrict__ ksc,
                                          const float* __restrict__ mnorm,
                                          float* __restrict__ out) {
  __shared__ __bf16 As[4096];
  __shared__ __bf16 Bs[8192];
  int tid = threadIdx.x;
  int bid = blockIdx.x;
  if (bid == 640) {  // new_memory_norm
    int d = tid;
    float s = 0.f;
    for (int c = 0; c < NCHT; ++c) s += ksc[c * DMEM + d];
    out[(size_t)MTOT * HIDDEN + DMEM * DMEM + d] = mnorm[d] + s * (1.f / (float)BATCH);
    return;
  }
  int lane = tid & 63, wave = tid >> 6;
  int wr = wave >> 1, wc = wave & 1, quad = lane >> 4, l16 = lane & 15;
  if (bid < 512) {  // output projection, 64x128 BK=64
    int m0 = (bid & 63) * 64, by = bid >> 6;  // by 0..7
    const __bf16* aptr = combb + (size_t)(m0 + (tid >> 2)) * DMEM + ((tid & 3) << 3);
    const __bf16* bptr = wob + (size_t)(by * 128 + (tid >> 2)) * DMEM + ((tid & 3) << 3);
    f32x4 acc[2][4] = {};
    gemm64_bk64(aptr, bptr, DMEM, DMEM, As, Bs, wave, wr, wc, quad, l16, acc);
#pragma unroll
    for (int i = 0; i < 2; ++i)
#pragma unroll
      for (int j = 0; j < 4; ++j)
#pragma unroll
        for (int r = 0; r < 4; ++r) {
          int m = m0 + wr * 32 + i * 16 + quad * 4 + r;
          int n = by * 128 + wc * 64 + j * 16 + l16;
          out[(size_t)m * HIDDEN + n] = acc[i][j][r];
        }
  } else {  // mem-update: 16-way split-K (K=256 each), 64x128 tiles, atomics
    int t = bid - 512;
    int kbase = (t >> 3) * 256;
    int yy = t & 7;
    int d0 = (yy >> 1) * 64, e0 = (yy & 1) * 128;
    const __bf16* aptr = skT + (size_t)(d0 + (tid >> 2)) * MTOT + kbase + ((tid & 3) << 3);
    const __bf16* bptr = dvT + (size_t)(e0 + (tid >> 2)) * MTOT + kbase + ((tid & 3) << 3);
    f32x4 acc[2][4] = {};
    gemm64_bk64(aptr, bptr, MTOT, 256, As, Bs, wave, wr, wc, quad, l16, acc);
    float* base = out + (size_t)MTOT * HIDDEN;
#pragma unroll
    for (int i = 0; i < 2; ++i)
#pragma unroll
      for (int j = 0; j < 4; ++j)
#pragma unroll
        for (int r = 0; r < 4; ++r) {
          int d = d0 + wr * 32 + i * 16 + quad * 4 + r;
          int e = e0 + wc * 64 + j * 16 + l16;
          atomicAdd(&base[(size_t)d * DMEM + e], acc[i][j][r] * (1.f / (float)MTOT));
        }
  }
}

extern "C" void kernel_launch(void* const* d_in, const int* in_sizes, int n_in,
                              void* d_out, int out_size, void* d_ws, size_t ws_size,
                              hipStream_t stream) {
  const float* hs = (const float*)d_in[0];
  const float* wq = (const float*)d_in[1];
  const float* wk = (const float*)d_in[2];
  const float* wv = (const float*)d_in[3];
  const float* wo = (const float*)d_in[4];
  const float* gate = (const float*)d_in[5];
  const float* mem = (const float*)d_in[6];
  const float* mnorm = (const float*)d_in[7];
  float* out = (float*)d_out;
  float* ws = (float*)d_ws;

  // fp32 region
  float* ksc = ws;          // 8192
  float* den = ksc + 8192;  // 4096
  float* qn = den + 4096;   // 4096
  float* kn = qn + 4096;    // 4096 (end 20480 floats)
  // bf16 region
  __bf16* kvcT = (__bf16*)(ws + 20480);               // 2097152
  __bf16* hsb = kvcT + (size_t)NCHT * DMEM * DMEM;    // 4194304
  __bf16* wqkvb = hsb + (size_t)MTOT * HIDDEN;        // 786432
  __bf16* wob = wqkvb + (size_t)3 * DMEM * HIDDEN;    // 262144
  __bf16* memT = wob + (size_t)HIDDEN * DMEM;         // 65536
  __bf16* sqb = memT + (size_t)DMEM * DMEM;           // 1048576
  __bf16* skb = sqb + (size_t)MTOT * DMEM;            // 1048576
  __bf16* skT = skb + (size_t)MTOT * DMEM;            // 1048576
  __bf16* vT = skT + (size_t)MTOT * DMEM;             // 1048576
  __bf16* scb = vT + (size_t)MTOT * DMEM;             // 524288
  __bf16* kvpT = scb + (size_t)NCHT * CHUNK * CHUNK;  // 2097152
  __bf16* combb = kvpT + (size_t)NCHT * DMEM * DMEM;  // 1048576
  __bf16* dvT = combb + (size_t)MTOT * DMEM;          // 1048576

  kprep<<<dim3(1360), 256, 0, stream>>>(hs, wq, wk, wv, wo, mem, hsb, wqkvb, wob, memT, out);
  k1_qkv_mfma<<<dim3(64, 6), 256, 0, stream>>>(hsb, wqkvb, sqb, skb, skT, vT);
  kC<<<dim3(NCHT, 11), 256, 0, stream>>>(vT, skT, sqb, skb, kvcT, scb, ksc);
  kD<<<dim3(1152), 256, 0, stream>>>(kvcT, kvpT, ksc, scb, sqb, skb, mnorm, den, qn, kn);
  kE<<<dim3(256), 256, 0, stream>>>(scb, sqb, skb, vT, kvpT, memT, den, qn, kn, gate, mnorm,
                                    combb, dvT);
  kF<<<dim3(641), 256, 0, stream>>>(combb, wob, skT, dvT, ksc, mnorm, out);
}